// Round 2
// baseline (107.337 us; speedup 1.0000x reference)
//
#include <hip/hip_runtime.h>
#include <hip/hip_bf16.h>

// KPConv collapses to: out[c,:] = sum_m s[c,m] * (x[src(c,m),:] @ W[m])
// with s[c,m] = sum of w over neighbors whose argmin kernel point == m.
// Stage 1: W fp32 [16][64][128] -> bf16 [16][128][64] (transposed) in ws.
// Stage 2: fused blocks of 16 centers: edge weights -> s (LDS, atomic-free),
//          then MFMA bf16 GEMM (M=16/block, N=128, K=1024, BK=64),
//          double-buffered LDS (1 barrier/iter), 2-deep register prefetch,
//          grid=512 -> 2 blocks/CU for cross-block latency overlap.

#define P 16
#define IN_F 64
#define OUT_F 128
#define NCC 8192
#define KPE 0.6666667f  // float(1.0/1.5), matches numpy f32 promotion

typedef short short8 __attribute__((ext_vector_type(8)));
typedef float floatx4 __attribute__((ext_vector_type(4)));

__device__ inline unsigned short f2bf(float f) {
    __hip_bfloat16 h = __float2bfloat16(f);
    return __builtin_bit_cast(unsigned short, h);
}

// W [m][i][n] fp32 -> Wb [m][n][i] bf16 (coalesced writes, strided reads; tiny)
__global__ __launch_bounds__(256) void kconv_w(const float* __restrict__ Wf,
                                               unsigned short* __restrict__ Wb) {
    int tg = blockIdx.x * 256 + threadIdx.x;   // 131072 total
    int m = tg >> 13;
    int n = (tg >> 6) & 127;
    int i = tg & 63;
    Wb[tg] = f2bf(Wf[(m * 64 + i) * 128 + n]);
}

__global__ __launch_bounds__(256) void kconv_main(
    const float* __restrict__ x, const float* __restrict__ pos,
    const int* __restrict__ esrc, const int* __restrict__ etgt,
    const float* __restrict__ kpts, const unsigned short* __restrict__ Wb,
    float* __restrict__ out)
{
    __shared__ float kps[48];
    __shared__ float wv[256];
    __shared__ int   nnv[256];
    __shared__ int   srcv[256];
    __shared__ float s_loc[256];                       // [16 centers][16 m]
    __shared__ __align__(16) unsigned short As[2][16 * 72];   // pad 64->72
    __shared__ __align__(16) unsigned short Bs[2][128 * 72];

    const int t   = threadIdx.x;                 // 256 threads = 4 waves
    const int c0  = blockIdx.x * 16;             // 16 centers per block

    if (t < 48) kps[t] = kpts[t];

    // ---- per-edge: argmin kernel point + linear influence weight ----
    // Exact-rounding ops: must bit-match numpy's fp32 sq so argmin agrees.
    const int e   = blockIdx.x * 256 + t;        // 256 edges per block
    const int src = esrc[e];
    const int tgt = etgt[e];
    float rx = __fsub_rn(pos[tgt * 3 + 0], pos[src * 3 + 0]);
    float ry = __fsub_rn(pos[tgt * 3 + 1], pos[src * 3 + 1]);
    float rz = __fsub_rn(pos[tgt * 3 + 2], pos[src * 3 + 2]);
    __syncthreads();                             // kps ready
    float best = 1e30f; int nn = 0;
#pragma unroll
    for (int k = 0; k < 16; ++k) {
        float dx = __fsub_rn(rx, kps[k * 3 + 0]);
        float dy = __fsub_rn(ry, kps[k * 3 + 1]);
        float dz = __fsub_rn(rz, kps[k * 3 + 2]);
        float sq = __fadd_rn(__fadd_rn(__fmul_rn(dx, dx), __fmul_rn(dy, dy)),
                             __fmul_rn(dz, dz));
        if (sq < best) { best = sq; nn = k; }    // strict < == first-min (np.argmin)
    }
    float w = fmaxf(__fsub_rn(1.0f, __fdiv_rn(__fsqrt_rn(best), KPE)), 0.0f);
    wv[t] = w; nnv[t] = nn; srcv[t] = src;
    __syncthreads();

    // ---- s[c,m] = sum of w where nn == m (atomic-free) ----
    {
        int cl = t >> 4, mm = t & 15;
        float sacc = 0.f;
#pragma unroll
        for (int n2 = 0; n2 < 16; ++n2) {
            int idx = cl * 16 + n2;
            sacc += (nnv[idx] == mm) ? wv[idx] : 0.f;
        }
        s_loc[t] = sacc;
    }

    // ---- GEMM setup ----
    const float4* x4  = reinterpret_cast<const float4*>(x);
    const uint4*  wb4 = reinterpret_cast<const uint4*>(Wb);   // 1024 uint4 per m
    const int ar = t >> 4, aq = t & 15;          // A-fill: row (center), quarter
    const int ar16 = ar * 16;

    // 2-deep register prefetch (srcv valid after the barrier above)
    float4 xa[2];
    uint4  bv[2][4];
    xa[0] = x4[srcv[ar16 + 0] * 16 + aq];
    xa[1] = x4[srcv[ar16 + 1] * 16 + aq];
#pragma unroll
    for (int j = 0; j < 4; ++j) {
        bv[0][j] = wb4[0 * 1024 + j * 256 + t];
        bv[1][j] = wb4[1 * 1024 + j * 256 + t];
    }
    __syncthreads();                             // s_loc ready

    // write buffer 0 (m=0)
    {
        float sv = s_loc[ar16 + 0];
        ushort4 av;
        av.x = f2bf(sv * xa[0].x); av.y = f2bf(sv * xa[0].y);
        av.z = f2bf(sv * xa[0].z); av.w = f2bf(sv * xa[0].w);
        *reinterpret_cast<ushort4*>(&As[0][ar * 72 + aq * 4]) = av;
#pragma unroll
        for (int j = 0; j < 4; ++j) {
            int u = j * 256 + t;                 // row = u>>3, seg = u&7
            *reinterpret_cast<uint4*>(&Bs[0][(u >> 3) * 72 + (u & 7) * 8]) = bv[0][j];
        }
    }

    const int wave = t >> 6, lane = t & 63;
    const int quad = lane >> 4, l16 = lane & 15;
    const int aoff  = l16 * 72;
    const int boff0 = ((wave * 2 + 0) * 16 + l16) * 72;
    const int boff1 = ((wave * 2 + 1) * 16 + l16) * 72;
    const int koff  = quad * 8;

    floatx4 acc0 = {0.f, 0.f, 0.f, 0.f};
    floatx4 acc1 = {0.f, 0.f, 0.f, 0.f};

#pragma unroll
    for (int m = 0; m < 16; ++m) {
        const int cur = m & 1, nxt = 1 - cur;
        __syncthreads();                         // buf[cur] writes visible

        // MFMA phase (reads buf[cur])
#pragma unroll
        for (int ks = 0; ks < 2; ++ks) {
            short8 a  = *reinterpret_cast<const short8*>(&As[cur][aoff  + ks * 32 + koff]);
            short8 b0 = *reinterpret_cast<const short8*>(&Bs[cur][boff0 + ks * 32 + koff]);
            acc0 = __builtin_amdgcn_mfma_f32_16x16x32_bf16(a, b0, acc0, 0, 0, 0);
            short8 b1 = *reinterpret_cast<const short8*>(&Bs[cur][boff1 + ks * 32 + koff]);
            acc1 = __builtin_amdgcn_mfma_f32_16x16x32_bf16(a, b1, acc1, 0, 0, 0);
        }

        if (m < 15) {
            // write buf[nxt] with data for m+1 (prefetched in set nxt)
            float sv = s_loc[ar16 + m + 1];
            ushort4 av;
            av.x = f2bf(sv * xa[nxt].x); av.y = f2bf(sv * xa[nxt].y);
            av.z = f2bf(sv * xa[nxt].z); av.w = f2bf(sv * xa[nxt].w);
            *reinterpret_cast<ushort4*>(&As[nxt][ar * 72 + aq * 4]) = av;
#pragma unroll
            for (int j = 0; j < 4; ++j) {
                int u = j * 256 + t;
                *reinterpret_cast<uint4*>(&Bs[nxt][(u >> 3) * 72 + (u & 7) * 8]) = bv[nxt][j];
            }
            if (m < 14) {
                // refill set[cur] with data for m+2
                xa[cur] = x4[srcv[ar16 + m + 2] * 16 + aq];
#pragma unroll
                for (int j = 0; j < 4; ++j)
                    bv[cur][j] = wb4[(m + 2) * 1024 + j * 256 + t];
            }
        }
    }

    // ---- epilogue: C/D layout col=lane&15, row=quad*4+reg ----
    const int col  = wave * 32 + l16;
    const int row0 = c0 + quad * 4;
#pragma unroll
    for (int v = 0; v < 4; ++v) {
        out[(row0 + v) * 128 + col]      = acc0[v];
        out[(row0 + v) * 128 + col + 16] = acc1[v];
    }
}

extern "C" void kernel_launch(void* const* d_in, const int* in_sizes, int n_in,
                              void* d_out, int out_size, void* d_ws, size_t ws_size,
                              hipStream_t stream) {
    const float* x    = (const float*)d_in[0];
    const float* pos  = (const float*)d_in[1];
    const int*   esrc = (const int*)d_in[2];
    const int*   etgt = (const int*)d_in[3];
    const float* kpts = (const float*)d_in[4];
    const float* Wf   = (const float*)d_in[5];
    float* out = (float*)d_out;
    unsigned short* Wb = (unsigned short*)d_ws;   // 262144 B used

    hipLaunchKernelGGL(kconv_w, dim3(512), dim3(256), 0, stream, Wf, Wb);
    hipLaunchKernelGGL(kconv_main, dim3(NCC / 16), dim3(256), 0, stream,
                       x, pos, esrc, etgt, kpts, Wb, out);
}

// Round 3
// 96.750 us; speedup vs baseline: 1.1094x; 1.1094x over previous
//
#include <hip/hip_runtime.h>
#include <hip/hip_bf16.h>

// KPConv collapses to: out[c,:] = sum_m s[c,m] * (x[src(c,m),:] @ W[m])
// with s[c,m] = sum of w over neighbors whose argmin kernel point == m.
//
// prep:  W fp32 [16][64][128] -> Wb bf16 [16][128][64] (LDS transpose) and
//        x fp32 [32768][64]   -> xb bf16 (both in d_ws; re-done every launch
//        since harness re-poisons ws).
// main:  per block: 32 centers. Prologue: exact-rounding argmin -> s[c,m]
//        (LDS, atomic-free). GEMM: barrier-free m-loop, MFMA fragments
//        loaded DIRECTLY from global (xb gather + Wb) in fragment layout,
//        s applied post-MFMA per m-block (acc += s_row * (x@W[m])), 1-deep
//        register pipeline, fully unrolled.

#define KPE 0.6666667f  // float(1.0/1.5), matches numpy f32 promotion

typedef short short8 __attribute__((ext_vector_type(8)));
typedef float floatx4 __attribute__((ext_vector_type(4)));

__device__ inline unsigned short f2bf(float f) {
    __hip_bfloat16 h = __float2bfloat16(f);
    return __builtin_bit_cast(unsigned short, h);
}

// blocks 0..15: transpose+convert W[m]; blocks 16..2063: convert x -> bf16
__global__ __launch_bounds__(256) void kconv_prep(const float* __restrict__ Wf,
                                                  const float* __restrict__ x,
                                                  unsigned short* __restrict__ Wb,
                                                  unsigned short* __restrict__ xb) {
    const int t = threadIdx.x;
    if (blockIdx.x < 16) {
        const int m = blockIdx.x;
        __shared__ float tile[64 * 129];            // [i][n], pad 128->129
#pragma unroll
        for (int j = 0; j < 32; ++j) {
            int idx = j * 256 + t;                  // i = idx>>7, n = idx&127
            tile[(idx >> 7) * 129 + (idx & 127)] = Wf[m * 8192 + idx];
        }
        __syncthreads();
#pragma unroll
        for (int j = 0; j < 32; ++j) {
            int idx = j * 256 + t;                  // n = idx>>6, i = idx&63
            Wb[m * 8192 + idx] = f2bf(tile[(idx & 63) * 129 + (idx >> 6)]);
        }
    } else {
        int idx4 = (blockIdx.x - 16) * 256 + t;     // float4 units, 524288 total
        const float4 v = reinterpret_cast<const float4*>(x)[idx4];
        ushort4 o;
        o.x = f2bf(v.x); o.y = f2bf(v.y); o.z = f2bf(v.z); o.w = f2bf(v.w);
        reinterpret_cast<ushort4*>(xb)[idx4] = o;
    }
}

__global__ __launch_bounds__(512) void kconv_main(
    const unsigned short* __restrict__ xb, const float* __restrict__ pos,
    const int* __restrict__ esrc, const int* __restrict__ etgt,
    const float* __restrict__ kpts, const unsigned short* __restrict__ Wb,
    float* __restrict__ out)
{
    __shared__ float kps[48];
    __shared__ float wv[32 * 17];                  // [r][n] pad 16->17
    __shared__ int   nnv[32 * 17];
    __shared__ int   srcv[16 * 32];                // [m][r]
    __shared__ __align__(16) float s_loc[16 * 32]; // [m][r]

    const int t = threadIdx.x;                     // 512 threads = 8 waves
    if (t < 48) kps[t] = kpts[t];

    // ---- per-edge: argmin kernel point + influence weight (bit-exact) ----
    const int e   = blockIdx.x * 512 + t;          // 32 centers * 16 edges
    const int src = esrc[e];
    const int tgt = etgt[e];
    float rx = __fsub_rn(pos[tgt * 3 + 0], pos[src * 3 + 0]);
    float ry = __fsub_rn(pos[tgt * 3 + 1], pos[src * 3 + 1]);
    float rz = __fsub_rn(pos[tgt * 3 + 2], pos[src * 3 + 2]);
    __syncthreads();                               // kps visible
    float best = 1e30f; int nn = 0;
#pragma unroll
    for (int k = 0; k < 16; ++k) {
        float dx = __fsub_rn(rx, kps[k * 3 + 0]);
        float dy = __fsub_rn(ry, kps[k * 3 + 1]);
        float dz = __fsub_rn(rz, kps[k * 3 + 2]);
        float sq = __fadd_rn(__fadd_rn(__fmul_rn(dx, dx), __fmul_rn(dy, dy)),
                             __fmul_rn(dz, dz));
        if (sq < best) { best = sq; nn = k; }      // strict < == np.argmin
    }
    float w = fmaxf(__fsub_rn(1.0f, __fdiv_rn(__fsqrt_rn(best), KPE)), 0.0f);
    {
        const int r = t >> 4, n = t & 15;
        wv[r * 17 + n] = w; nnv[r * 17 + n] = nn;
        srcv[n * 32 + r] = src;                    // [m][r] layout
    }
    __syncthreads();

    // ---- s[c,m] = sum of w where nn == m ----
    {
        const int m = t >> 5, rr = t & 31;
        float sacc = 0.f;
#pragma unroll
        for (int n2 = 0; n2 < 16; ++n2)
            sacc += (nnv[rr * 17 + n2] == m) ? wv[rr * 17 + n2] : 0.f;
        s_loc[m * 32 + rr] = sacc;
    }
    __syncthreads();                               // last barrier

    // ---- barrier-free MFMA GEMM: 32 rows x 128 cols, K = 16 m-blocks x 64 ----
    const uint4* xb4 = reinterpret_cast<const uint4*>(xb);   // 8 uint4 / row
    const uint4* wb4 = reinterpret_cast<const uint4*>(Wb);   // 1024 uint4 / m
    const int wave = t >> 6, lane = t & 63;
    const int rg = wave & 1, cq = wave >> 2 ? (wave >> 1) & 3 : (wave >> 1) & 3;
    const int l16 = lane & 15, quad = lane >> 4;
    const int cqq = wave >> 1;                     // 0..3 column quarter
    const int arow = rg * 16 + l16;                // row within block (A frag)
    const int bq0 = (cqq * 32 + l16) * 8 + quad;   // B frag base, ct=0
    const int bq1 = bq0 + 16 * 8;                  // ct=1
    const int svoff = rg * 16 + quad * 4;          // s float4 offset

    uint4 A[2][2], B[2][4];
    float4 SV[2];
    {
        int s0 = srcv[arow];
        A[0][0] = xb4[s0 * 8 + quad];
        A[0][1] = xb4[s0 * 8 + 4 + quad];
        B[0][0] = wb4[bq0];
        B[0][1] = wb4[bq0 + 4];
        B[0][2] = wb4[bq1];
        B[0][3] = wb4[bq1 + 4];
        SV[0] = *reinterpret_cast<const float4*>(&s_loc[svoff]);
    }

    floatx4 acc0 = {0.f, 0.f, 0.f, 0.f};
    floatx4 acc1 = {0.f, 0.f, 0.f, 0.f};
    const floatx4 zed = {0.f, 0.f, 0.f, 0.f};

#pragma unroll
    for (int m = 0; m < 16; ++m) {
        const int cur = m & 1, nxt = cur ^ 1;
        if (m < 15) {                              // prefetch m+1
            int sn = srcv[(m + 1) * 32 + arow];
            A[nxt][0] = xb4[sn * 8 + quad];
            A[nxt][1] = xb4[sn * 8 + 4 + quad];
            const int wb = (m + 1) * 1024;
            B[nxt][0] = wb4[wb + bq0];
            B[nxt][1] = wb4[wb + bq0 + 4];
            B[nxt][2] = wb4[wb + bq1];
            B[nxt][3] = wb4[wb + bq1 + 4];
            SV[nxt] = *reinterpret_cast<const float4*>(&s_loc[(m + 1) * 32 + svoff]);
        }
        short8 a0 = __builtin_bit_cast(short8, A[cur][0]);
        short8 a1 = __builtin_bit_cast(short8, A[cur][1]);
        floatx4 t0 = __builtin_amdgcn_mfma_f32_16x16x32_bf16(
            a0, __builtin_bit_cast(short8, B[cur][0]), zed, 0, 0, 0);
        t0 = __builtin_amdgcn_mfma_f32_16x16x32_bf16(
            a1, __builtin_bit_cast(short8, B[cur][1]), t0, 0, 0, 0);
        floatx4 t1 = __builtin_amdgcn_mfma_f32_16x16x32_bf16(
            a0, __builtin_bit_cast(short8, B[cur][2]), zed, 0, 0, 0);
        t1 = __builtin_amdgcn_mfma_f32_16x16x32_bf16(
            a1, __builtin_bit_cast(short8, B[cur][3]), t1, 0, 0, 0);
        const float4 sv = SV[cur];
#pragma unroll
        for (int v = 0; v < 4; ++v) {
            const float s4 = (v == 0) ? sv.x : (v == 1) ? sv.y : (v == 2) ? sv.z : sv.w;
            acc0[v] += s4 * t0[v];
            acc1[v] += s4 * t1[v];
        }
    }

    // ---- epilogue: C/D layout col=lane&15, row=quad*4+reg ----
    const int col  = cqq * 32 + l16;
    const int row0 = blockIdx.x * 32 + rg * 16 + quad * 4;
#pragma unroll
    for (int v = 0; v < 4; ++v) {
        out[(row0 + v) * 128 + col]      = acc0[v];
        out[(row0 + v) * 128 + col + 16] = acc1[v];
    }
}

extern "C" void kernel_launch(void* const* d_in, const int* in_sizes, int n_in,
                              void* d_out, int out_size, void* d_ws, size_t ws_size,
                              hipStream_t stream) {
    const float* x    = (const float*)d_in[0];
    const float* pos  = (const float*)d_in[1];
    const int*   esrc = (const int*)d_in[2];
    const int*   etgt = (const int*)d_in[3];
    const float* kpts = (const float*)d_in[4];
    const float* Wf   = (const float*)d_in[5];
    float* out = (float*)d_out;

    char* wsb = (char*)d_ws;
    unsigned short* Wb = (unsigned short*)wsb;              // 262144 B
    unsigned short* xb = (unsigned short*)(wsb + 262144);   // 4 MiB

    hipLaunchKernelGGL(kconv_prep, dim3(16 + 2048), dim3(256), 0, stream,
                       Wf, x, Wb, xb);
    hipLaunchKernelGGL(kconv_main, dim3(256), dim3(512), 0, stream,
                       xb, pos, esrc, etgt, kpts, Wb, out);
}